// Round 7
// baseline (161.416 us; speedup 1.0000x reference)
//
#include <hip/hip_runtime.h>
#include <stdint.h>

typedef unsigned int u32;
typedef unsigned long long u64;
typedef unsigned short u16;
typedef unsigned char u8;

#define NPTS 8192
#define CAP 32

// ---------------------------------------------------------------------------
// A: rank by counting + scatter into rank space. 256 blocks x 1024 threads.
// (unchanged from r5/r6 -- left the top-5 there)
// ---------------------------------------------------------------------------
__global__ __launch_bounds__(1024) void k_rank(const float* __restrict__ coords,
                                               const float* __restrict__ scores,
                                               u32* __restrict__ sorted_id,
                                               float* __restrict__ sx,
                                               float* __restrict__ sy,
                                               float* __restrict__ ss,
                                               u32* __restrict__ nbr_cnt) {
  __shared__ u32 skey[NPTS];
  int t = threadIdx.x, B = blockIdx.x;
  for (int k = t; k < NPTS; k += 1024) skey[k] = __float_as_uint(scores[k]);
  if (B == 0) {
    for (int k = t; k < NPTS; k += 1024) nbr_cnt[k] = 0;
  }
  __syncthreads();

  int s = t & 31;   // slice 0..31, 256 keys each
  int g = t >> 5;   // point group 0..31
  int p = B * 32 + g;
  u32 kp = skey[p];
  const uint4* k4 = (const uint4*)skey;
  int b4 = s << 6;
  u32 c = 0;
#pragma unroll 4
  for (int j = 0; j < 64; ++j) {
    int jj = (j + s) & 63;  // rotate across bank groups (4-way alias, 1.58x)
    uint4 kv = k4[b4 + jj];
    int q = (s << 8) + (jj << 2);
    c += (kv.x > kp || (kv.x == kp && q + 0 < p)) ? 1u : 0u;
    c += (kv.y > kp || (kv.y == kp && q + 1 < p)) ? 1u : 0u;
    c += (kv.z > kp || (kv.z == kp && q + 2 < p)) ? 1u : 0u;
    c += (kv.w > kp || (kv.w == kp && q + 3 < p)) ? 1u : 0u;
  }
  c += __shfl_xor(c, 1);
  c += __shfl_xor(c, 2);
  c += __shfl_xor(c, 4);
  c += __shfl_xor(c, 8);
  c += __shfl_xor(c, 16);
  if (s == 0) {
    sorted_id[c] = (u32)p;
    sx[c] = coords[2 * p];      // bitwise copies keep arithmetic exact
    sy[c] = coords[2 * p + 1];
    ss[c] = scores[p];
  }
}

// ---------------------------------------------------------------------------
// B: higher-priority in-radius neighbor lists (triangular tile grid,
// bitmask inner loop). Unchanged from r6 -- left the top-5 there.
// ---------------------------------------------------------------------------
__global__ __launch_bounds__(256) void k_nbr(const float* __restrict__ sx,
                                             const float* __restrict__ sy,
                                             u32* __restrict__ nbr_cnt,
                                             u16* __restrict__ nbr) {
  __shared__ float qx[128], qy[128];
  int b = blockIdx.x;
  int R = (int)((__fsqrt_rn(4.0f * (float)b + 1.0f) - 1.0f) * 0.5f);
  while ((R + 1) * (R + 2) <= b) ++R;
  while (R * (R + 1) > b) --R;
  int C = b - R * (R + 1);
  int t = threadIdx.x;
  int q0 = C << 7;
  int r = (R << 8) + t;
  if (t < 128) qx[t] = sx[q0 + t];
  else         qy[t - 128] = sy[q0 + t - 128];
  __syncthreads();

  float x = sx[r], y = sy[r];
  int jlim = 128;
  int dC = C - 2 * R;
  if (dC >= 0) {
    jlim = t - (dC << 7);
    if (jlim < 0) jlim = 0;
    if (jlim > 128) jlim = 128;
  }
  const float4* x4 = (const float4*)qx;
  const float4* y4 = (const float4*)qy;
  for (int jg = 0; jg < 4; ++jg) {
    int base = jg << 5;
    int v = jlim - base;
    u32 gm = (v >= 32) ? 0xFFFFFFFFu : ((v <= 0) ? 0u : ((1u << v) - 1u));
    u32 m = 0;
#pragma unroll
    for (int j4 = 0; j4 < 8; ++j4) {
      float4 xv = x4[(base >> 2) + j4];
      float4 yv = y4[(base >> 2) + j4];
      float dx0 = __fsub_rn(x, xv.x), dy0 = __fsub_rn(y, yv.x);
      float dx1 = __fsub_rn(x, xv.y), dy1 = __fsub_rn(y, yv.y);
      float dx2 = __fsub_rn(x, xv.z), dy2 = __fsub_rn(y, yv.z);
      float dx3 = __fsub_rn(x, xv.w), dy3 = __fsub_rn(y, yv.w);
      if (__fadd_rn(__fmul_rn(dx0, dx0), __fmul_rn(dy0, dy0)) < 64.0f) m |= 1u << (4 * j4 + 0);
      if (__fadd_rn(__fmul_rn(dx1, dx1), __fmul_rn(dy1, dy1)) < 64.0f) m |= 1u << (4 * j4 + 1);
      if (__fadd_rn(__fmul_rn(dx2, dx2), __fmul_rn(dy2, dy2)) < 64.0f) m |= 1u << (4 * j4 + 2);
      if (__fadd_rn(__fmul_rn(dx3, dx3), __fmul_rn(dy3, dy3)) < 64.0f) m |= 1u << (4 * j4 + 3);
    }
    m &= gm;
    while (m) {
      int j2 = __builtin_ctz(m);
      m &= m - 1;
      u32 sl = atomicAdd(&nbr_cnt[r], 1u);
      if (sl < CAP) nbr[(size_t)sl * NPTS + r] = (u16)(q0 + base + j2);
    }
  }
}

// ---------------------------------------------------------------------------
// C: chunk-serial pipelined ballot NMS (1 block, 16 waves, 1 CU).
// 128 chunks of 64 ranks; wave w owns chunks w, w+16, ... Dependencies only
// flow low rank -> high rank, so resolving chunks in order is EXACT greedy.
// Pre-wait (overlapped): classify my <=CAP neighbors --
//   rank < 64*(c-15): chunk final (acq/rel chain) -> check keep bit now
//   rank in [64*(c-15), 64c): bank into 2 u64 regs (8 slots; overflow->rescan)
//   rank in my chunk: set bit in 64-bit in-chunk lane mask
// Post-wait (serial spine, ~0.5 LDS bit reads + 2 ballots + rare resolve
// loop + release store): ~200 cyc x 128 chunks ~= 10 us.
// Spin has a bounded guard (wrong-answer-not-hang safety valve).
// ---------------------------------------------------------------------------
__global__ __launch_bounds__(1024) void k_nms(const u32* __restrict__ nbr_cnt,
                                              const u16* __restrict__ nbr,
                                              const u32* __restrict__ sorted_id,
                                              const float* __restrict__ ss,
                                              float* __restrict__ out) {
  __shared__ u32 keepw[NPTS / 32];  // keep bitmask, 1 bit per rank
  __shared__ int done;              // next chunk index to resolve
  int t = threadIdx.x;
  int w = t >> 6, lane = t & 63;
  if (t < NPTS / 32) keepw[t] = 0;
  if (t == 0) done = 0;
  __syncthreads();

  for (int ci = 0; ci < 8; ++ci) {
    int c = w + (ci << 4);
    int S = c << 6;
    int r = S + lane;
    int oldLim = (c - 15) << 6;
    if (oldLim < 0) oldLim = 0;

    // ---- pre-wait: load + classify neighbors ----
    u32 cnt = nbr_cnt[r];
    if (cnt > CAP) cnt = CAP;
    bool suppOld = false;
    u64 inmask = 0;
    u64 rlo = 0, rhi = 0;
    u32 nrec = 0;
    for (u32 n = 0; n < cnt; ++n) {
      u32 q = nbr[(size_t)n * NPTS + r];
      if ((int)q < oldLim) {
        u32 wv = __hip_atomic_load(&keepw[q >> 5], __ATOMIC_RELAXED,
                                   __HIP_MEMORY_SCOPE_WORKGROUP);
        suppOld |= ((wv >> (q & 31)) & 1u) != 0u;
      } else if ((int)q < S) {
        if (nrec < 4) rlo |= (u64)q << (nrec * 16);
        else if (nrec < 8) rhi |= (u64)q << ((nrec - 4) * 16);
        nrec++;
      } else {
        inmask |= 1ull << (q - S);  // q in [S, r): earlier lane in my chunk
      }
    }

    // ---- spin until all chunks < c are resolved (same-addr LDS broadcast)
    long guard = 0;
    while (__hip_atomic_load(&done, __ATOMIC_ACQUIRE,
                             __HIP_MEMORY_SCOPE_WORKGROUP) < c) {
      if (++guard > (8L << 20)) break;  // safety valve
    }

    // ---- post-wait: recent-neighbor checks (now final) ----
    bool supp = suppOld;
    if (nrec <= 8) {
      for (u32 i2 = 0; i2 < nrec; ++i2) {
        u32 q = (u32)(((i2 < 4) ? (rlo >> (i2 * 16)) : (rhi >> ((i2 - 4) * 16))) & 0xFFFFull);
        u32 wv = __hip_atomic_load(&keepw[q >> 5], __ATOMIC_RELAXED,
                                   __HIP_MEMORY_SCOPE_WORKGROUP);
        supp |= ((wv >> (q & 31)) & 1u) != 0u;
      }
    } else {  // ultra-rare overflow: rescan global list (all < S final now)
      for (u32 n = 0; n < cnt; ++n) {
        u32 q = nbr[(size_t)n * NPTS + r];
        if ((int)q < S && (int)q >= oldLim) {
          u32 wv = __hip_atomic_load(&keepw[q >> 5], __ATOMIC_RELAXED,
                                     __HIP_MEMORY_SCOPE_WORKGROUP);
          supp |= ((wv >> (q & 31)) & 1u) != 0u;
        }
      }
    }

    // ---- in-chunk resolve: exact greedy over 64 lanes ----
    u64 cand = __ballot(!supp);        // alive after external suppression
    u64 haveM = __ballot(inmask != 0); // lanes with in-chunk deps
    u64 keepm = cand & ~haveM;         // no in-chunk deps -> kept iff alive
    u64 undec = cand & haveM;
    while (undec) {  // expected ~1-2 iterations (in-chunk edges are rare)
      int l = __builtin_ctzll(undec);
      u64 im = __shfl((unsigned long long)inmask, l);  // inmask of lane l
      if ((im & keepm) == 0) keepm |= 1ull << l;       // earlier lanes decided
      undec &= undec - 1;
    }

    // ---- publish chunk result + release ----
    if (lane == 0) {
      __hip_atomic_store(&keepw[c * 2], (u32)keepm, __ATOMIC_RELAXED,
                         __HIP_MEMORY_SCOPE_WORKGROUP);
      __hip_atomic_store(&keepw[c * 2 + 1], (u32)(keepm >> 32), __ATOMIC_RELAXED,
                         __HIP_MEMORY_SCOPE_WORKGROUP);
      __hip_atomic_store(&done, c + 1, __ATOMIC_RELEASE,
                         __HIP_MEMORY_SCOPE_WORKGROUP);
    }
  }
  __syncthreads();

  // epilogue: keep mask (original order) + suppressed scores (rank order)
  for (int k = t; k < NPTS; k += 1024) {
    u32 kp = (keepw[k >> 5] >> (k & 31)) & 1u;
    out[sorted_id[k]] = kp ? 1.0f : 0.0f;
    out[NPTS + k] = kp ? ss[k] : 0.0f;
  }
}

// ---------------------------------------------------------------------------
extern "C" void kernel_launch(void* const* d_in, const int* in_sizes, int n_in,
                              void* d_out, int out_size, void* d_ws, size_t ws_size,
                              hipStream_t stream) {
  const float* coords = (const float*)d_in[0];  // [N,2]
  const float* scores = (const float*)d_in[1];  // [N]
  float* out = (float*)d_out;                   // [N keep | N suppressed scores]

  char* ws = (char*)d_ws;
  size_t off = 0;
  u16* nbr       = (u16*)(ws + off); off += (size_t)CAP * NPTS * 2;  // 512K
  u32* sorted_id = (u32*)(ws + off); off += (size_t)NPTS * 4;        // 32K
  float* sx      = (float*)(ws + off); off += (size_t)NPTS * 4;      // 32K
  float* sy      = (float*)(ws + off); off += (size_t)NPTS * 4;      // 32K
  float* ss      = (float*)(ws + off); off += (size_t)NPTS * 4;      // 32K
  u32* nbr_cnt   = (u32*)(ws + off); off += (size_t)NPTS * 4;        // 32K

  k_rank<<<256, 1024, 0, stream>>>(coords, scores, sorted_id, sx, sy, ss, nbr_cnt);
  k_nbr<<<32 * 33, 256, 0, stream>>>(sx, sy, nbr_cnt, nbr);
  k_nms<<<1, 1024, 0, stream>>>(nbr_cnt, nbr, sorted_id, ss, out);
}

// Round 8
// 136.012 us; speedup vs baseline: 1.1868x; 1.1868x over previous
//
#include <hip/hip_runtime.h>
#include <stdint.h>

typedef unsigned int u32;
typedef unsigned long long u64;
typedef unsigned short u16;
typedef unsigned char u8;

#define NPTS 8192
#define CAP 32
#define SEG2 2048
#define NROW 8

// ---------------------------------------------------------------------------
// A: rank by counting + scatter into rank space. 256 blocks x 1024 threads.
// (unchanged from r5-r7 -- kept fixed for attribution)
// ---------------------------------------------------------------------------
__global__ __launch_bounds__(1024) void k_rank(const float* __restrict__ coords,
                                               const float* __restrict__ scores,
                                               u32* __restrict__ sorted_id,
                                               float* __restrict__ sx,
                                               float* __restrict__ sy,
                                               float* __restrict__ ss,
                                               u32* __restrict__ nbr_cnt) {
  __shared__ u32 skey[NPTS];
  int t = threadIdx.x, B = blockIdx.x;
  for (int k = t; k < NPTS; k += 1024) skey[k] = __float_as_uint(scores[k]);
  if (B == 0) {
    for (int k = t; k < NPTS; k += 1024) nbr_cnt[k] = 0;
  }
  __syncthreads();

  int s = t & 31;   // slice 0..31, 256 keys each
  int g = t >> 5;   // point group 0..31
  int p = B * 32 + g;
  u32 kp = skey[p];
  const uint4* k4 = (const uint4*)skey;
  int b4 = s << 6;
  u32 c = 0;
#pragma unroll 4
  for (int j = 0; j < 64; ++j) {
    int jj = (j + s) & 63;
    uint4 kv = k4[b4 + jj];
    int q = (s << 8) + (jj << 2);
    c += (kv.x > kp || (kv.x == kp && q + 0 < p)) ? 1u : 0u;
    c += (kv.y > kp || (kv.y == kp && q + 1 < p)) ? 1u : 0u;
    c += (kv.z > kp || (kv.z == kp && q + 2 < p)) ? 1u : 0u;
    c += (kv.w > kp || (kv.w == kp && q + 3 < p)) ? 1u : 0u;
  }
  c += __shfl_xor(c, 1);
  c += __shfl_xor(c, 2);
  c += __shfl_xor(c, 4);
  c += __shfl_xor(c, 8);
  c += __shfl_xor(c, 16);
  if (s == 0) {
    sorted_id[c] = (u32)p;
    sx[c] = coords[2 * p];      // bitwise copies keep arithmetic exact
    sy[c] = coords[2 * p + 1];
    ss[c] = scores[p];
  }
}

// ---------------------------------------------------------------------------
// B: higher-priority in-radius neighbor lists (triangular tile grid,
// bitmask inner loop). Unchanged from r6/r7 -- kept fixed for attribution.
// ---------------------------------------------------------------------------
__global__ __launch_bounds__(256) void k_nbr(const float* __restrict__ sx,
                                             const float* __restrict__ sy,
                                             u32* __restrict__ nbr_cnt,
                                             u16* __restrict__ nbr) {
  __shared__ float qx[128], qy[128];
  int b = blockIdx.x;
  int R = (int)((__fsqrt_rn(4.0f * (float)b + 1.0f) - 1.0f) * 0.5f);
  while ((R + 1) * (R + 2) <= b) ++R;
  while (R * (R + 1) > b) --R;
  int C = b - R * (R + 1);
  int t = threadIdx.x;
  int q0 = C << 7;
  int r = (R << 8) + t;
  if (t < 128) qx[t] = sx[q0 + t];
  else         qy[t - 128] = sy[q0 + t - 128];
  __syncthreads();

  float x = sx[r], y = sy[r];
  int jlim = 128;
  int dC = C - 2 * R;
  if (dC >= 0) {
    jlim = t - (dC << 7);
    if (jlim < 0) jlim = 0;
    if (jlim > 128) jlim = 128;
  }
  const float4* x4 = (const float4*)qx;
  const float4* y4 = (const float4*)qy;
  for (int jg = 0; jg < 4; ++jg) {
    int base = jg << 5;
    int v = jlim - base;
    u32 gm = (v >= 32) ? 0xFFFFFFFFu : ((v <= 0) ? 0u : ((1u << v) - 1u));
    u32 m = 0;
#pragma unroll
    for (int j4 = 0; j4 < 8; ++j4) {
      float4 xv = x4[(base >> 2) + j4];
      float4 yv = y4[(base >> 2) + j4];
      float dx0 = __fsub_rn(x, xv.x), dy0 = __fsub_rn(y, yv.x);
      float dx1 = __fsub_rn(x, xv.y), dy1 = __fsub_rn(y, yv.y);
      float dx2 = __fsub_rn(x, xv.z), dy2 = __fsub_rn(y, yv.z);
      float dx3 = __fsub_rn(x, xv.w), dy3 = __fsub_rn(y, yv.w);
      if (__fadd_rn(__fmul_rn(dx0, dx0), __fmul_rn(dy0, dy0)) < 64.0f) m |= 1u << (4 * j4 + 0);
      if (__fadd_rn(__fmul_rn(dx1, dx1), __fmul_rn(dy1, dy1)) < 64.0f) m |= 1u << (4 * j4 + 1);
      if (__fadd_rn(__fmul_rn(dx2, dx2), __fmul_rn(dy2, dy2)) < 64.0f) m |= 1u << (4 * j4 + 2);
      if (__fadd_rn(__fmul_rn(dx3, dx3), __fmul_rn(dy3, dy3)) < 64.0f) m |= 1u << (4 * j4 + 3);
    }
    m &= gm;
    while (m) {
      int j2 = __builtin_ctz(m);
      m &= m - 1;
      u32 sl = atomicAdd(&nbr_cnt[r], 1u);
      if (sl < CAP) nbr[(size_t)sl * NPTS + r] = (u16)(q0 + base + j2);
    }
  }
}

// ---------------------------------------------------------------------------
// C: segmented pull-fixpoint, registers-only lists (1 block, 1024 thr).
// 4 segments of 2048 ranks, 2 points/thread. Round 0 per segment: prefix
// neighbors checked against FINAL keep bits; in-segment neighbors marked in
// a per-point 8-bit register mask (rows 0..7 prefetched one segment early,
// coalesced). Eval rounds: 8 masked single-level ds_read_u8 of keep[] per
// point (parallel, break-free), Gauss-Seidel DOUBLE-pass per barrier to
// halve round count. Rare cnt>8 tail rescans global. Rotating 4-slot flag:
// 1 barrier/round; flag==0 after a round => no writes occurred => fixpoint.
// Serial budget ~16 rounds x ~400cyc -- the r7 chain had 128 links.
// ---------------------------------------------------------------------------
__global__ __launch_bounds__(1024) void k_nms(const u32* __restrict__ nbr_cnt,
                                              const u16* __restrict__ nbr,
                                              const u32* __restrict__ sorted_id,
                                              const float* __restrict__ ss,
                                              float* __restrict__ out) {
  __shared__ u8 keep[NPTS];
  __shared__ int slot[4];
  int t = threadIdx.x;

  // prefetch segment 0: counts + rows 0..7 for points (t, 1024+t)
  u32 cA_n = nbr_cnt[t], cB_n = nbr_cnt[1024 + t];
  u16 eA_n[NROW], eB_n[NROW];
#pragma unroll
  for (int n = 0; n < NROW; ++n) {
    eA_n[n] = nbr[n * NPTS + t];
    eB_n[n] = nbr[n * NPTS + 1024 + t];
  }

  for (int s = 0; s < 4; ++s) {
    int segbase = s << 11;
    int pA = segbase + t, pB = segbase + 1024 + t;
    u32 cA = cA_n, cB = cB_n;
    if (cA > CAP) cA = CAP;
    if (cB > CAP) cB = CAP;
    u16 eA[NROW], eB[NROW];
#pragma unroll
    for (int n = 0; n < NROW; ++n) { eA[n] = eA_n[n]; eB[n] = eB_n[n]; }

    if (s < 3) {  // issue next segment's loads now; waited on next iteration
      int b = segbase + SEG2;
      cA_n = nbr_cnt[b + t];
      cB_n = nbr_cnt[b + 1024 + t];
#pragma unroll
      for (int n = 0; n < NROW; ++n) {
        eA_n[n] = nbr[n * NPTS + b + t];
        eB_n[n] = nbr[n * NPTS + b + 1024 + t];
      }
    }

    // ---- round 0: prefix suppression (final bits) + in-segment reg masks
    bool supA = false, supB = false;
    u32 mA = 0, mB = 0;
#pragma unroll
    for (int n = 0; n < NROW; ++n) {
      if (n < (int)cA) {
        int q = eA[n];
        if (q < segbase) supA |= (keep[q] != 0);
        else mA |= 1u << n;
      }
      if (n < (int)cB) {
        int q = eB[n];
        if (q < segbase) supB |= (keep[q] != 0);
        else mB |= 1u << n;
      }
    }
    bool tailA = (cA > NROW), tailB = (cB > NROW);
    for (u32 n = NROW; n < cA; ++n) {  // rare tail (P(cnt>8) small)
      int q = nbr[n * NPTS + pA];
      if (q < segbase) supA |= (keep[q] != 0);
    }
    for (u32 n = NROW; n < cB; ++n) {
      int q = nbr[n * NPTS + pB];
      if (q < segbase) supB |= (keep[q] != 0);
    }
    keep[pA] = supA ? (u8)0 : (u8)1;
    keep[pB] = supB ? (u8)0 : (u8)1;
    bool actA = !supA && (mA != 0 || tailA);
    bool actB = !supB && (mB != 0 || tailB);
    if (t < 4) slot[t] = 0;  // benign 0-over-0 race vs prev segment exit read
    __syncthreads();

    // ---- eval rounds: double-pass Gauss-Seidel, 1 barrier/round
    for (int r = 1; r <= SEG2 + 2; ++r) {
      if (t == 0) slot[(r + 2) & 3] = 0;
      bool flip = false;
#pragma unroll
      for (int pass = 0; pass < 2; ++pass) {
        if (actA) {
          bool dead = false;
#pragma unroll
          for (int n = 0; n < NROW; ++n)
            if ((mA >> n) & 1) dead |= (keep[eA[n]] != 0);
          if (tailA)
            for (u32 n = NROW; n < cA; ++n) {
              int q = nbr[n * NPTS + pA];
              if (q >= segbase) dead |= (keep[q] != 0);
            }
          u8 a = dead ? (u8)0 : (u8)1;
          if (keep[pA] != a) { keep[pA] = a; flip = true; }
        }
        if (actB) {
          bool dead = false;
#pragma unroll
          for (int n = 0; n < NROW; ++n)
            if ((mB >> n) & 1) dead |= (keep[eB[n]] != 0);
          if (tailB)
            for (u32 n = NROW; n < cB; ++n) {
              int q = nbr[n * NPTS + pB];
              if (q >= segbase) dead |= (keep[q] != 0);
            }
          u8 a = dead ? (u8)0 : (u8)1;
          if (keep[pB] != a) { keep[pB] = a; flip = true; }
        }
      }
      if (flip) slot[r & 3] = 1;
      __syncthreads();
      if (slot[r & 3] == 0) break;  // no writes in a full round: fixpoint
    }
  }

  // epilogue: keep mask (original order) + suppressed scores (rank order)
  for (int k = t; k < NPTS; k += 1024) {
    u8 kp = keep[k];
    out[sorted_id[k]] = kp ? 1.0f : 0.0f;
    out[NPTS + k] = kp ? ss[k] : 0.0f;
  }
}

// ---------------------------------------------------------------------------
extern "C" void kernel_launch(void* const* d_in, const int* in_sizes, int n_in,
                              void* d_out, int out_size, void* d_ws, size_t ws_size,
                              hipStream_t stream) {
  const float* coords = (const float*)d_in[0];  // [N,2]
  const float* scores = (const float*)d_in[1];  // [N]
  float* out = (float*)d_out;                   // [N keep | N suppressed scores]

  char* ws = (char*)d_ws;
  size_t off = 0;
  u16* nbr       = (u16*)(ws + off); off += (size_t)CAP * NPTS * 2;  // 512K
  u32* sorted_id = (u32*)(ws + off); off += (size_t)NPTS * 4;        // 32K
  float* sx      = (float*)(ws + off); off += (size_t)NPTS * 4;      // 32K
  float* sy      = (float*)(ws + off); off += (size_t)NPTS * 4;      // 32K
  float* ss      = (float*)(ws + off); off += (size_t)NPTS * 4;      // 32K
  u32* nbr_cnt   = (u32*)(ws + off); off += (size_t)NPTS * 4;        // 32K

  k_rank<<<256, 1024, 0, stream>>>(coords, scores, sorted_id, sx, sy, ss, nbr_cnt);
  k_nbr<<<32 * 33, 256, 0, stream>>>(sx, sy, nbr_cnt, nbr);
  k_nms<<<1, 1024, 0, stream>>>(nbr_cnt, nbr, sorted_id, ss, out);
}